// Round 1
// baseline (1372.269 us; speedup 1.0000x reference)
//
#include <hip/hip_runtime.h>
#include <hip/hip_bf16.h>

// Problem constants
#define SS 2048
#define DD 1024
#define HH 16
#define DU 64
#define SD (SS*DD)   // 2097152 floats per S x D buffer

// ---------------------------------------------------------------------------
// Generic fp32 tiled GEMM: C[M,N] = A[M,K] @ B[K,N]
// BM=128, BN=64, BK=16, block 16x16, each thread 8x4 micro-tile.
// ---------------------------------------------------------------------------
__global__ __launch_bounds__(256) void gemm_f32(const float* __restrict__ A,
                                                const float* __restrict__ B,
                                                float* __restrict__ C,
                                                int M, int N, int K) {
    __shared__ __align__(16) float As[16][128 + 4];  // As[k][m]
    __shared__ __align__(16) float Bs[16][64 + 4];   // Bs[k][n]
    const int tx = threadIdx.x;       // 0..15
    const int ty = threadIdx.y;       // 0..15
    const int tid = ty * 16 + tx;
    const int row0 = blockIdx.y * 128;
    const int col0 = blockIdx.x * 64;

    float acc[8][4];
#pragma unroll
    for (int i = 0; i < 8; ++i)
#pragma unroll
        for (int j = 0; j < 4; ++j) acc[i][j] = 0.f;

    for (int k0 = 0; k0 < K; k0 += 16) {
        // Load A tile: 128 rows x 16 k = 512 float4, 256 threads -> 2 each
#pragma unroll
        for (int it = 0; it < 2; ++it) {
            int f = it * 256 + tid;
            int r = f >> 2;            // 0..127
            int kq = (f & 3) * 4;      // 0,4,8,12
            float4 av = *(const float4*)(A + (size_t)(row0 + r) * K + k0 + kq);
            As[kq + 0][r] = av.x;
            As[kq + 1][r] = av.y;
            As[kq + 2][r] = av.z;
            As[kq + 3][r] = av.w;
        }
        // Load B tile: 16 rows x 64 cols = 256 float4, 1 each
        {
            int kr = tid >> 4;          // 0..15
            int nc = (tid & 15) * 4;    // 0..60
            *(float4*)&Bs[kr][nc] =
                *(const float4*)(B + (size_t)(k0 + kr) * N + col0 + nc);
        }
        __syncthreads();
#pragma unroll
        for (int k = 0; k < 16; ++k) {
            float a[8], b[4];
            *(float4*)&a[0] = *(const float4*)&As[k][ty * 8];
            *(float4*)&a[4] = *(const float4*)&As[k][ty * 8 + 4];
            *(float4*)&b[0] = *(const float4*)&Bs[k][tx * 4];
#pragma unroll
            for (int i = 0; i < 8; ++i)
#pragma unroll
                for (int j = 0; j < 4; ++j) acc[i][j] += a[i] * b[j];
        }
        __syncthreads();
    }
#pragma unroll
    for (int i = 0; i < 8; ++i) {
        float4 o = make_float4(acc[i][0], acc[i][1], acc[i][2], acc[i][3]);
        *(float4*)(C + (size_t)(row0 + ty * 8 + i) * N + col0 + tx * 4) = o;
    }
}

// ---------------------------------------------------------------------------
// RoPE + sigmoid, in-place on Q and K buffers (layout [S][D], D = H*DU).
// One thread per (which, s, h, i) pair, i in [0,32).
// ---------------------------------------------------------------------------
__global__ __launch_bounds__(256) void rope_sig(float* __restrict__ Qb,
                                                float* __restrict__ Kb,
                                                const float* __restrict__ fc,
                                                const float* __restrict__ fs) {
    int idx = blockIdx.x * 256 + threadIdx.x;   // 0 .. 2*S*H*32-1
    int i  = idx & 31;
    int h  = (idx >> 5) & 15;
    int s_ = (idx >> 9) & 2047;
    float* buf = (idx >> 20) ? Kb : Qb;         // 2^20 == S*H*32
    size_t off = (size_t)s_ * DD + h * DU + 2 * i;
    float2 ab = *(float2*)(buf + off);
    float c  = fc[s_ * 32 + i];
    float sn = fs[s_ * 32 + i];
    float na = ab.x * c - ab.y * sn;
    float nb = ab.x * sn + ab.y * c;
    ab.x = 1.f / (1.f + __expf(-na));
    ab.y = 1.f / (1.f + __expf(-nb));
    *(float2*)(buf + off) = ab;
}

// ---------------------------------------------------------------------------
// Attention with the "topos" score: t = sum_d relu(q_d - k_d),
// score = 5*(1 - t/64); softmax shift by the fixed upper bound 5 gives
// p = exp(-5t/64) -- no running max, so k-split partials are additive.
// Grid: (q-chunks=32, k-splits=8, heads=16), block = 64 threads (1 wave),
// one thread owns one q row; partial (acc,l) atomically added to ws.
// ---------------------------------------------------------------------------
#define TK 16
__global__ __launch_bounds__(64) void attn_kernel(const float* __restrict__ Q,
                                                  const float* __restrict__ K,
                                                  const float* __restrict__ V,
                                                  float* __restrict__ AO,
                                                  float* __restrict__ L) {
    __shared__ __align__(16) float Ks[TK][DU + 4];
    __shared__ __align__(16) float Vs[TK][DU + 4];
    __shared__ float Sks[TK];
    const int tid = threadIdx.x;     // 0..63
    const int qc  = blockIdx.x;      // 0..31
    const int ks  = blockIdx.y;      // 0..7
    const int h   = blockIdx.z;      // 0..15
    const int q0  = qc * 64;
    const int q   = q0 + tid;
    const int klo = ks * 256;
    int khi = klo + 256;
    int kcap = q0 + 64;              // causal cap (max q in block is q0+63)
    if (khi > kcap) khi = kcap;
    if (klo >= khi) return;          // fully masked block (uniform exit)

    // Load this thread's q row and its sum
    float qv[DU];
    float sq = 0.f;
    const float* qp = Q + (size_t)q * DD + h * DU;
#pragma unroll
    for (int d4 = 0; d4 < DU / 4; ++d4) {
        float4 f = ((const float4*)qp)[d4];
        qv[4 * d4 + 0] = f.x; qv[4 * d4 + 1] = f.y;
        qv[4 * d4 + 2] = f.z; qv[4 * d4 + 3] = f.w;
        sq += (f.x + f.y) + (f.z + f.w);
    }

    float acc[DU];
#pragma unroll
    for (int d = 0; d < DU; ++d) acc[d] = 0.f;
    float l = 0.f;

    for (int k0 = klo; k0 < khi; k0 += TK) {
        __syncthreads();
        // Stage K,V tile: TK x DU = 256 float4 each, 64 threads -> 4 each
#pragma unroll
        for (int it = 0; it < 4; ++it) {
            int f = it * 64 + tid;     // 0..255
            int r = f >> 4;            // 0..15
            int c4 = f & 15;           // 0..15
            size_t src = (size_t)(k0 + r) * DD + h * DU + c4 * 4;
            *(float4*)&Ks[r][c4 * 4] = *(const float4*)(K + src);
            *(float4*)&Vs[r][c4 * 4] = *(const float4*)(V + src);
        }
        __syncthreads();
        // Per-row K sums (for the |.| trick)
        if (tid < TK) {
            float s = 0.f;
#pragma unroll
            for (int d = 0; d < DU; ++d) s += Ks[tid][d];
            Sks[tid] = s;
        }
        __syncthreads();

        for (int kk = 0; kk < TK; ++kk) {
            const int kidx = k0 + kk;
            float t0 = 0.f, t1 = 0.f, t2 = 0.f, t3 = 0.f;
#pragma unroll
            for (int d4 = 0; d4 < DU / 4; ++d4) {
                float4 kf = *(const float4*)&Ks[kk][d4 * 4];
                t0 += fabsf(qv[4 * d4 + 0] - kf.x);
                t1 += fabsf(qv[4 * d4 + 1] - kf.y);
                t2 += fabsf(qv[4 * d4 + 2] - kf.z);
                t3 += fabsf(qv[4 * d4 + 3] - kf.w);
            }
            float tsum = (t0 + t1) + (t2 + t3);
            float t = 0.5f * (sq - Sks[kk] + tsum);   // sum relu(q-k)
            float p = (kidx <= q) ? __expf(-0.078125f * t) : 0.f;  // -5/64
            l += p;
#pragma unroll
            for (int d4 = 0; d4 < DU / 4; ++d4) {
                float4 vf = *(const float4*)&Vs[kk][d4 * 4];
                acc[4 * d4 + 0] += p * vf.x;
                acc[4 * d4 + 1] += p * vf.y;
                acc[4 * d4 + 2] += p * vf.z;
                acc[4 * d4 + 3] += p * vf.w;
            }
        }
    }

    // Add partials (k-splits are additive thanks to the fixed softmax shift)
    float* aop = AO + (size_t)q * DD + h * DU;
#pragma unroll
    for (int d = 0; d < DU; ++d) atomicAdd(&aop[d], acc[d]);
    atomicAdd(&L[q * HH + h], l);
}

// ---------------------------------------------------------------------------
// Normalize: AO[s, h*64+d] /= L[s,h]
// ---------------------------------------------------------------------------
__global__ __launch_bounds__(256) void norm_kernel(float* __restrict__ AO,
                                                   const float* __restrict__ L) {
    int idx = blockIdx.x * 256 + threadIdx.x;   // one float4 each, SD/4 total
    int c4 = idx & (DD / 4 - 1);                // 0..255
    int s_ = idx >> 8;
    float li = L[s_ * HH + (c4 >> 4)];
    float inv = 1.f / li;
    float4 v = ((float4*)AO)[idx];
    v.x *= inv; v.y *= inv; v.z *= inv; v.w *= inv;
    ((float4*)AO)[idx] = v;
}

// ---------------------------------------------------------------------------
extern "C" void kernel_launch(void* const* d_in, const int* in_sizes, int n_in,
                              void* d_out, int out_size, void* d_ws, size_t ws_size,
                              hipStream_t stream) {
    const float* x  = (const float*)d_in[0];
    const float* fc = (const float*)d_in[1];
    const float* fs = (const float*)d_in[2];
    // d_in[3] = mask (causality implemented directly)
    const float* Wq = (const float*)d_in[4];
    const float* Wk = (const float*)d_in[5];
    const float* Wv = (const float*)d_in[6];
    const float* Wo = (const float*)d_in[7];
    float* out = (float*)d_out;

    float* Qw = (float*)d_ws;          // ws usage: 4*SD + S*H floats = 33.7 MB
    float* Kw = Qw + SD;
    float* Vw = Kw + SD;
    float* AO = Vw + SD;
    float* Lw = AO + SD;

    dim3 gemmGrid(DD / 64, SS / 128);  // (16,16)
    dim3 gemmBlk(16, 16);

    // QKV projections
    gemm_f32<<<gemmGrid, gemmBlk, 0, stream>>>(x, Wq, Qw, SS, DD, DD);
    gemm_f32<<<gemmGrid, gemmBlk, 0, stream>>>(x, Wk, Kw, SS, DD, DD);
    gemm_f32<<<gemmGrid, gemmBlk, 0, stream>>>(x, Wv, Vw, SS, DD, DD);

    // RoPE + sigmoid on Q,K (in place)
    rope_sig<<<(2 * SS * HH * 32) / 256, 256, 0, stream>>>(Qw, Kw, fc, fs);

    // Zero attention accumulators (AO and L are contiguous)
    hipMemsetAsync(AO, 0, (size_t)(SD + SS * HH) * sizeof(float), stream);

    // Fused truth/softmax/PV attention
    attn_kernel<<<dim3(32, 8, HH), 64, 0, stream>>>(Qw, Kw, Vw, AO, Lw);

    // Normalize by softmax denominator
    norm_kernel<<<SD / 4 / 256, 256, 0, stream>>>(AO, Lw);

    // Output projection
    gemm_f32<<<gemmGrid, gemmBlk, 0, stream>>>(AO, Wo, out, SS, DD, DD);
}

// Round 2
// 1014.425 us; speedup vs baseline: 1.3528x; 1.3528x over previous
//
#include <hip/hip_runtime.h>

#define SS 2048
#define DD 1024
#define HH 16
#define DUx 64
#define SD (SS*DD)

typedef __attribute__((ext_vector_type(8))) _Float16 half8;
typedef __attribute__((ext_vector_type(4))) float f32x4;

__device__ __forceinline__ float h2f(unsigned short u) {
    union { unsigned short s; _Float16 h; } v; v.s = u; return (float)v.h;
}
__device__ __forceinline__ unsigned short f2h(float f) {
    union { _Float16 h; unsigned short s; } v; v.h = (_Float16)f; return v.s;
}

// ---------------------------------------------------------------------------
// fp32 -> f16 convert (x -> Xb), 8 elements/thread
// ---------------------------------------------------------------------------
__global__ __launch_bounds__(256) void cvt_f16(const float* __restrict__ X,
                                               unsigned short* __restrict__ Xb) {
    int i = (blockIdx.x * 256 + threadIdx.x) * 8;
    float4 f0 = *(const float4*)(X + i);
    float4 f1 = *(const float4*)(X + i + 4);
    ushort4 o0, o1;
    o0.x = f2h(f0.x); o0.y = f2h(f0.y); o0.z = f2h(f0.z); o0.w = f2h(f0.w);
    o1.x = f2h(f1.x); o1.y = f2h(f1.y); o1.z = f2h(f1.z); o1.w = f2h(f1.w);
    *(ushort4*)(Xb + i) = o0;
    *(ushort4*)(Xb + i + 4) = o1;
}

// ---------------------------------------------------------------------------
// Transpose + convert: Wt[c][r] = f16(W[r][c]).  32x32 tiles, block (32,8).
// ---------------------------------------------------------------------------
__global__ __launch_bounds__(256) void transpose_cvt(const float* __restrict__ W,
                                                     unsigned short* __restrict__ Wt,
                                                     int rows, int cols) {
    __shared__ float T[32][33];
    const int tx = threadIdx.x;          // 0..31
    const int ty = threadIdx.y;          // 0..7
    const int c0 = blockIdx.x * 32, r0 = blockIdx.y * 32;
#pragma unroll
    for (int j = 0; j < 4; ++j) {
        int r = ty * 4 + j;
        T[r][tx] = W[(size_t)(r0 + r) * cols + c0 + tx];
    }
    __syncthreads();
#pragma unroll
    for (int j = 0; j < 4; ++j) {
        int c = ty * 4 + j;
        Wt[(size_t)(c0 + c) * rows + r0 + tx] = f2h(T[tx][c]);
    }
}

// ---------------------------------------------------------------------------
// f16 MFMA GEMM: C[M,N] = A[M,K] @ Bt[N,K]^T.  128x128 tile, BK=32, 4 waves.
// MODE 0: write f16 into 3-way split (Qb|Kb|Vb), each 1024 cols.
// MODE 1: write fp32 into Cf[M,N].
// Fragment layout (verified m89/m91): A lane l holds A[l&15][(l>>4)*8+j];
// C/D: col=lane&15, row=(lane>>4)*4+reg.
// ---------------------------------------------------------------------------
template <int MODE>
__global__ __launch_bounds__(256) void gemm_f16(const unsigned short* __restrict__ A,
                                                const unsigned short* __restrict__ Bt,
                                                unsigned short* __restrict__ Qo,
                                                unsigned short* __restrict__ Ko,
                                                unsigned short* __restrict__ Vo,
                                                float* __restrict__ Cf,
                                                int M, int N, int K) {
    __shared__ __align__(16) unsigned short As[128 * 32];
    __shared__ __align__(16) unsigned short Bs[128 * 32];
    const int tid = threadIdx.x;
    const int l = tid & 63, w = tid >> 6;
    const int wr = w >> 1, wc = w & 1;
    const int row0 = blockIdx.y * 128, col0 = blockIdx.x * 128;

    f32x4 acc[4][4] = {};

    for (int k0 = 0; k0 < K; k0 += 32) {
        __syncthreads();
#pragma unroll
        for (int it = 0; it < 2; ++it) {
            int f = it * 256 + tid;
            int r = f >> 2, seg = f & 3;
            *(half8*)&As[r * 32 + seg * 8] =
                *(const half8*)(A + (size_t)(row0 + r) * K + k0 + seg * 8);
            *(half8*)&Bs[r * 32 + seg * 8] =
                *(const half8*)(Bt + (size_t)(col0 + r) * K + k0 + seg * 8);
        }
        __syncthreads();
        half8 a[4], b[4];
#pragma unroll
        for (int m = 0; m < 4; ++m) {
            int r = wr * 64 + m * 16 + (l & 15);
            a[m] = *(const half8*)&As[r * 32 + (l >> 4) * 8];
        }
#pragma unroll
        for (int n = 0; n < 4; ++n) {
            int r = wc * 64 + n * 16 + (l & 15);
            b[n] = *(const half8*)&Bs[r * 32 + (l >> 4) * 8];
        }
#pragma unroll
        for (int m = 0; m < 4; ++m)
#pragma unroll
            for (int n = 0; n < 4; ++n)
                acc[m][n] = __builtin_amdgcn_mfma_f32_16x16x32_f16(a[m], b[n], acc[m][n], 0, 0, 0);
    }

    const int lr = (l >> 4) * 4, lc = l & 15;
    if (MODE == 0) {
        int third = col0 >> 10;
        unsigned short* Cp = third == 0 ? Qo : (third == 1 ? Ko : Vo);
        int cb = (col0 & 1023) + wc * 64;
#pragma unroll
        for (int m = 0; m < 4; ++m)
#pragma unroll
            for (int n = 0; n < 4; ++n)
#pragma unroll
                for (int e = 0; e < 4; ++e) {
                    int row = row0 + wr * 64 + m * 16 + lr + e;
                    Cp[(size_t)row * DD + cb + n * 16 + lc] = f2h(acc[m][n][e]);
                }
    } else {
#pragma unroll
        for (int m = 0; m < 4; ++m)
#pragma unroll
            for (int n = 0; n < 4; ++n)
#pragma unroll
                for (int e = 0; e < 4; ++e) {
                    int row = row0 + wr * 64 + m * 16 + lr + e;
                    Cf[(size_t)row * N + col0 + wc * 64 + n * 16 + lc] = acc[m][n][e];
                }
    }
}

// ---------------------------------------------------------------------------
// RoPE + sigmoid in place on f16 Q,K. One thread per (which,s,h,i), i<32.
// ---------------------------------------------------------------------------
__global__ __launch_bounds__(256) void rope_sig(unsigned short* __restrict__ Qb,
                                                unsigned short* __restrict__ Kb,
                                                const float* __restrict__ fc,
                                                const float* __restrict__ fs) {
    int idx = blockIdx.x * 256 + threadIdx.x;
    int i = idx & 31;
    int h = (idx >> 5) & 15;
    int s_ = (idx >> 9) & 2047;
    unsigned short* buf = (idx >> 20) ? Kb : Qb;
    size_t off = (size_t)s_ * DD + h * DUx + 2 * i;
    unsigned int u = *(const unsigned int*)(buf + off);
    float a = h2f((unsigned short)(u & 0xFFFF));
    float b = h2f((unsigned short)(u >> 16));
    float c = fc[s_ * 32 + i];
    float sn = fs[s_ * 32 + i];
    float na = a * c - b * sn;
    float nb = a * sn + b * c;
    float sa = 1.f / (1.f + __expf(-na));
    float sb = 1.f / (1.f + __expf(-nb));
    unsigned int o = (unsigned int)f2h(sa) | ((unsigned int)f2h(sb) << 16);
    *(unsigned int*)(buf + off) = o;
}

// ---------------------------------------------------------------------------
// Per-(s,h) K row sums. 4 lanes per pair, quad shuffle reduce.
// ---------------------------------------------------------------------------
__global__ __launch_bounds__(256) void ksum_kernel(const unsigned short* __restrict__ Kb,
                                                   float* __restrict__ Ksum) {
    int tid = threadIdx.x;
    int p = blockIdx.x * 64 + (tid >> 2);
    int dg = tid & 3;
    int s_ = p >> 4, h = p & 15;
    const unsigned short* kp = Kb + (size_t)s_ * DD + h * DUx + dg * 16;
    float t = 0.f;
#pragma unroll
    for (int j4 = 0; j4 < 4; ++j4) {
        ushort4 u = *(const ushort4*)(kp + j4 * 4);
        t += (h2f(u.x) + h2f(u.y)) + (h2f(u.z) + h2f(u.w));
    }
    t += __shfl_xor(t, 1);
    t += __shfl_xor(t, 2);
    if (dg == 0) Ksum[p] = t;
}

// ---------------------------------------------------------------------------
// Attention: t = sum_d relu(q-k) = 0.5*(sq - sk + sum|q-k|); p = exp(-5t/64)
// (fixed softmax shift by the score upper bound 5 -> k-split partials add).
// Block 256 thr = 4 waves; wave = 16 q-rows x 4 lanes (16 dims each).
// Grid (qc=32, ksplit=8, h=16); partials atomically added into AO, L.
// ---------------------------------------------------------------------------
#define TK 32
__global__ __launch_bounds__(256) void attn_kernel(const unsigned short* __restrict__ Qb,
                                                   const unsigned short* __restrict__ Kb,
                                                   const unsigned short* __restrict__ Vb,
                                                   const float* __restrict__ Ksum,
                                                   float* __restrict__ AO,
                                                   float* __restrict__ L) {
    __shared__ __align__(16) float Ks[TK][DUx];
    __shared__ __align__(16) float Vs[TK][DUx];
    __shared__ float Ksm[TK];
    const int tid = threadIdx.x;
    const int l = tid & 63;
    const int w = tid >> 6;
    const int qc = blockIdx.x, ks = blockIdx.y, h = blockIdx.z;
    const int klo = ks * 256;
    int khi = klo + 256;
    const int kcap = qc * 64 + 64;
    if (khi > kcap) khi = kcap;
    if (klo >= khi) return;                      // block-uniform exit
    const int qr = l >> 2, dg = l & 3;
    const int q = qc * 64 + w * 16 + qr;

    float qv[16];
    float sq = 0.f;
    {
        const unsigned short* qp = Qb + (size_t)q * DD + h * DUx + dg * 16;
#pragma unroll
        for (int j4 = 0; j4 < 4; ++j4) {
            ushort4 u = *(const ushort4*)(qp + j4 * 4);
            qv[j4 * 4 + 0] = h2f(u.x); qv[j4 * 4 + 1] = h2f(u.y);
            qv[j4 * 4 + 2] = h2f(u.z); qv[j4 * 4 + 3] = h2f(u.w);
            sq += (qv[j4 * 4 + 0] + qv[j4 * 4 + 1]) + (qv[j4 * 4 + 2] + qv[j4 * 4 + 3]);
        }
        sq += __shfl_xor(sq, 1);
        sq += __shfl_xor(sq, 2);
    }

    float acc[16];
#pragma unroll
    for (int j = 0; j < 16; ++j) acc[j] = 0.f;
    float lsum = 0.f;

    const int sr = tid >> 4;            // staging row (and +16)
    const int sc = (tid & 15) * 4;      // staging col

    for (int k0 = klo; k0 < khi; k0 += TK) {
        __syncthreads();
#pragma unroll
        for (int hf = 0; hf < 2; ++hf) {
            int r = sr + hf * 16;
            size_t src = (size_t)(k0 + r) * DD + h * DUx + sc;
            ushort4 ku = *(const ushort4*)(Kb + src);
            ushort4 vu = *(const ushort4*)(Vb + src);
            float4 kf, vf;
            kf.x = h2f(ku.x); kf.y = h2f(ku.y); kf.z = h2f(ku.z); kf.w = h2f(ku.w);
            vf.x = h2f(vu.x); vf.y = h2f(vu.y); vf.z = h2f(vu.z); vf.w = h2f(vu.w);
            *(float4*)&Ks[r][sc] = kf;
            *(float4*)&Vs[r][sc] = vf;
        }
        if (tid < TK) Ksm[tid] = Ksum[(size_t)(k0 + tid) * HH + h];
        __syncthreads();

#pragma unroll 4
        for (int kk = 0; kk < TK; ++kk) {
            const float* kr = &Ks[kk][dg * 16];
            float t0 = 0.f, t1 = 0.f, t2 = 0.f, t3 = 0.f;
#pragma unroll
            for (int j4 = 0; j4 < 4; ++j4) {
                float4 kf = *(const float4*)(kr + j4 * 4);
                t0 += fabsf(qv[j4 * 4 + 0] - kf.x);
                t1 += fabsf(qv[j4 * 4 + 1] - kf.y);
                t2 += fabsf(qv[j4 * 4 + 2] - kf.z);
                t3 += fabsf(qv[j4 * 4 + 3] - kf.w);
            }
            float t = (t0 + t1) + (t2 + t3);
            t += __shfl_xor(t, 1);
            t += __shfl_xor(t, 2);
            float p = __expf(-0.0390625f * (sq - Ksm[kk] + t));  // -(5/64)*0.5
            p = (k0 + kk <= q) ? p : 0.f;
            lsum += p;
            const float* vr = &Vs[kk][dg * 16];
#pragma unroll
            for (int j4 = 0; j4 < 4; ++j4) {
                float4 vf = *(const float4*)(vr + j4 * 4);
                acc[j4 * 4 + 0] = fmaf(p, vf.x, acc[j4 * 4 + 0]);
                acc[j4 * 4 + 1] = fmaf(p, vf.y, acc[j4 * 4 + 1]);
                acc[j4 * 4 + 2] = fmaf(p, vf.z, acc[j4 * 4 + 2]);
                acc[j4 * 4 + 3] = fmaf(p, vf.w, acc[j4 * 4 + 3]);
            }
        }
    }

    float* aop = AO + (size_t)q * DD + h * DUx + dg * 16;
#pragma unroll
    for (int j = 0; j < 16; ++j) atomicAdd(aop + j, acc[j]);
    if (dg == 0) atomicAdd(&L[q * HH + h], lsum);
}

// ---------------------------------------------------------------------------
// Normalize AO by L and emit f16 for the output GEMM.
// ---------------------------------------------------------------------------
__global__ __launch_bounds__(256) void norm_kernel(const float* __restrict__ AO,
                                                   const float* __restrict__ L,
                                                   unsigned short* __restrict__ AOb) {
    int idx = blockIdx.x * 256 + threadIdx.x;   // SD/4 threads, float4 each
    int c4 = idx & 255;
    int s_ = idx >> 8;
    float inv = 1.f / L[s_ * HH + (c4 >> 4)];
    float4 v = ((const float4*)AO)[idx];
    ushort4 o;
    o.x = f2h(v.x * inv); o.y = f2h(v.y * inv);
    o.z = f2h(v.z * inv); o.w = f2h(v.w * inv);
    *(ushort4*)(AOb + (size_t)idx * 4) = o;
}

// ---------------------------------------------------------------------------
extern "C" void kernel_launch(void* const* d_in, const int* in_sizes, int n_in,
                              void* d_out, int out_size, void* d_ws, size_t ws_size,
                              hipStream_t stream) {
    const float* x  = (const float*)d_in[0];
    const float* fc = (const float*)d_in[1];
    const float* fs = (const float*)d_in[2];
    const float* Wq = (const float*)d_in[4];
    const float* Wk = (const float*)d_in[5];
    const float* Wv = (const float*)d_in[6];
    const float* Wo = (const float*)d_in[7];
    float* out = (float*)d_out;

    char* ws = (char*)d_ws;                                  // ~32.3 MB used
    unsigned short* Xb  = (unsigned short*)(ws);             // 4 MB (reused as AOb)
    unsigned short* Wt  = (unsigned short*)(ws + (4u << 20));   // 6 MB  QKV^T f16
    unsigned short* Wot = (unsigned short*)(ws + (10u << 20));  // 2 MB  Wo^T f16
    unsigned short* Qb  = (unsigned short*)(ws + (12u << 20));  // 4 MB
    unsigned short* Kb  = (unsigned short*)(ws + (16u << 20));  // 4 MB
    unsigned short* Vb  = (unsigned short*)(ws + (20u << 20));  // 4 MB
    float* AO   = (float*)(ws + (24u << 20));                   // 8 MB
    float* Lw   = (float*)(ws + (32u << 20));                   // 128 KB
    float* Ksum = (float*)(ws + (32u << 20) + SS * HH * 4);     // 128 KB
    unsigned short* AOb = Xb;

    cvt_f16<<<SD / 8 / 256, 256, 0, stream>>>(x, Xb);
    transpose_cvt<<<dim3(32, 32), dim3(32, 8), 0, stream>>>(Wq, Wt, DD, DD);
    transpose_cvt<<<dim3(32, 32), dim3(32, 8), 0, stream>>>(Wk, Wt + DD * DD, DD, DD);
    transpose_cvt<<<dim3(32, 32), dim3(32, 8), 0, stream>>>(Wv, Wt + 2 * DD * DD, DD, DD);
    transpose_cvt<<<dim3(32, 32), dim3(32, 8), 0, stream>>>(Wo, Wot, DD, DD);

    gemm_f16<0><<<dim3(24, 16), 256, 0, stream>>>(Xb, Wt, Qb, Kb, Vb, nullptr,
                                                  SS, 3 * DD, DD);
    rope_sig<<<8192, 256, 0, stream>>>(Qb, Kb, fc, fs);
    ksum_kernel<<<SS * HH / 64, 256, 0, stream>>>(Kb, Ksum);

    hipMemsetAsync(AO, 0, (size_t)SD * 4 + SS * HH * 4, stream);
    attn_kernel<<<dim3(32, 8, 16), 256, 0, stream>>>(Qb, Kb, Vb, Ksum, AO, Lw);
    norm_kernel<<<SD / 4 / 256, 256, 0, stream>>>(AO, Lw, AOb);

    gemm_f16<1><<<dim3(8, 16), 256, 0, stream>>>(AOb, Wot, nullptr, nullptr, nullptr,
                                                 out, SS, DD, DD);
}

// Round 10
// 339.501 us; speedup vs baseline: 4.0420x; 2.9880x over previous
//
#include <hip/hip_runtime.h>

#define SS 2048
#define DD 1024
#define HH 16
#define SD (SS*DD)

typedef __attribute__((ext_vector_type(8))) _Float16 half8;
typedef __attribute__((ext_vector_type(2))) _Float16 h2;
typedef __attribute__((ext_vector_type(4))) float f32x4;

__device__ __forceinline__ float h2f(unsigned short u) {
    union { unsigned short s; _Float16 h; } v; v.s = u; return (float)v.h;
}
__device__ __forceinline__ unsigned short f2h(float f) {
    union { _Float16 h; unsigned short s; } v; v.h = (_Float16)f; return v.s;
}

// ---------------------------------------------------------------------------
// fp32 -> f16 convert (x -> Xb), 8 elements/thread
// ---------------------------------------------------------------------------
__global__ __launch_bounds__(256) void cvt_f16(const float* __restrict__ X,
                                               unsigned short* __restrict__ Xb) {
    int i = (blockIdx.x * 256 + threadIdx.x) * 8;
    float4 f0 = *(const float4*)(X + i);
    float4 f1 = *(const float4*)(X + i + 4);
    ushort4 o0, o1;
    o0.x = f2h(f0.x); o0.y = f2h(f0.y); o0.z = f2h(f0.z); o0.w = f2h(f0.w);
    o1.x = f2h(f1.x); o1.y = f2h(f1.y); o1.z = f2h(f1.z); o1.w = f2h(f1.w);
    *(ushort4*)(Xb + i) = o0;
    *(ushort4*)(Xb + i + 4) = o1;
}

// ---------------------------------------------------------------------------
// Transpose + convert: Wt[c][r] = f16(W[r][c]).  32x32 tiles, block (32,8).
// ---------------------------------------------------------------------------
__global__ __launch_bounds__(256) void transpose_cvt(const float* __restrict__ W,
                                                     unsigned short* __restrict__ Wt,
                                                     int rows, int cols) {
    __shared__ float T[32][33];
    const int tx = threadIdx.x;
    const int ty = threadIdx.y;
    const int c0 = blockIdx.x * 32, r0 = blockIdx.y * 32;
#pragma unroll
    for (int j = 0; j < 4; ++j) {
        int r = ty * 4 + j;
        T[r][tx] = W[(size_t)(r0 + r) * cols + c0 + tx];
    }
    __syncthreads();
#pragma unroll
    for (int j = 0; j < 4; ++j) {
        int c = ty * 4 + j;
        Wt[(size_t)(c0 + c) * rows + r0 + tx] = f2h(T[tx][c]);
    }
}

// ---------------------------------------------------------------------------
// f16 MFMA GEMM: C[M,N] = A[M,K] @ Bt[N,K]^T.  128x128 tile, BK=32, 4 waves.
// MODE 0: cols [0,1024)->Qb f16, [1024,2048)->Kb f16,
//         [2048,3072)->Vt f16 TRANSPOSED (Vt[d][s], d = col-2048).
// MODE 1: write fp32 into Cf[M,N].
// ---------------------------------------------------------------------------
template <int MODE>
__global__ __launch_bounds__(256) void gemm_f16(const unsigned short* __restrict__ A,
                                                const unsigned short* __restrict__ Bt,
                                                unsigned short* __restrict__ Qo,
                                                unsigned short* __restrict__ Ko,
                                                unsigned short* __restrict__ Vt,
                                                float* __restrict__ Cf,
                                                int M, int N, int K) {
    __shared__ __align__(16) unsigned short As[128 * 32];
    __shared__ __align__(16) unsigned short Bs[128 * 32];
    const int tid = threadIdx.x;
    const int l = tid & 63, w = tid >> 6;
    const int wr = w >> 1, wc = w & 1;
    const int row0 = blockIdx.y * 128, col0 = blockIdx.x * 128;

    f32x4 acc[4][4] = {};

    for (int k0 = 0; k0 < K; k0 += 32) {
        __syncthreads();
#pragma unroll
        for (int it = 0; it < 2; ++it) {
            int f = it * 256 + tid;
            int r = f >> 2, seg = f & 3;
            *(half8*)&As[r * 32 + seg * 8] =
                *(const half8*)(A + (size_t)(row0 + r) * K + k0 + seg * 8);
            *(half8*)&Bs[r * 32 + seg * 8] =
                *(const half8*)(Bt + (size_t)(col0 + r) * K + k0 + seg * 8);
        }
        __syncthreads();
        half8 a[4], b[4];
#pragma unroll
        for (int m = 0; m < 4; ++m) {
            int r = wr * 64 + m * 16 + (l & 15);
            a[m] = *(const half8*)&As[r * 32 + (l >> 4) * 8];
        }
#pragma unroll
        for (int n = 0; n < 4; ++n) {
            int r = wc * 64 + n * 16 + (l & 15);
            b[n] = *(const half8*)&Bs[r * 32 + (l >> 4) * 8];
        }
#pragma unroll
        for (int m = 0; m < 4; ++m)
#pragma unroll
            for (int n = 0; n < 4; ++n)
                acc[m][n] = __builtin_amdgcn_mfma_f32_16x16x32_f16(a[m], b[n], acc[m][n], 0, 0, 0);
    }

    const int lr = (l >> 4) * 4, lc = l & 15;
    if (MODE == 0) {
        int third = col0 >> 10;
        if (third < 2) {
            unsigned short* Cp = third == 0 ? Qo : Ko;
            int cb = (col0 & 1023) + wc * 64;
#pragma unroll
            for (int m = 0; m < 4; ++m)
#pragma unroll
                for (int n = 0; n < 4; ++n)
#pragma unroll
                    for (int e = 0; e < 4; ++e) {
                        int row = row0 + wr * 64 + m * 16 + lr + e;
                        Cp[(size_t)row * DD + cb + n * 16 + lc] = f2h(acc[m][n][e]);
                    }
        } else {
            // transposed V write: Vt[d][s], 4 consecutive s packed per store
            int cb = (col0 & 1023) + wc * 64;
#pragma unroll
            for (int m = 0; m < 4; ++m)
#pragma unroll
                for (int n = 0; n < 4; ++n) {
                    int dcol = cb + n * 16 + lc;
                    int srow = row0 + wr * 64 + m * 16 + lr;
                    ushort4 o;
                    o.x = f2h(acc[m][n][0]); o.y = f2h(acc[m][n][1]);
                    o.z = f2h(acc[m][n][2]); o.w = f2h(acc[m][n][3]);
                    *(ushort4*)(Vt + (size_t)dcol * SS + srow) = o;
                }
        }
    } else {
#pragma unroll
        for (int m = 0; m < 4; ++m)
#pragma unroll
            for (int n = 0; n < 4; ++n)
#pragma unroll
                for (int e = 0; e < 4; ++e) {
                    int row = row0 + wr * 64 + m * 16 + lr + e;
                    Cf[(size_t)row * N + col0 + wc * 64 + n * 16 + lc] = acc[m][n][e];
                }
    }
}

// ---------------------------------------------------------------------------
// RoPE + sigmoid in place on f16 Q,K.
// ---------------------------------------------------------------------------
__global__ __launch_bounds__(256) void rope_sig(unsigned short* __restrict__ Qb,
                                                unsigned short* __restrict__ Kb,
                                                const float* __restrict__ fc,
                                                const float* __restrict__ fs) {
    int idx = blockIdx.x * 256 + threadIdx.x;
    int i = idx & 31;
    int h = (idx >> 5) & 15;
    int s_ = (idx >> 9) & 2047;
    unsigned short* buf = (idx >> 20) ? Kb : Qb;
    size_t off = (size_t)s_ * DD + h * 64 + 2 * i;
    unsigned int u = *(const unsigned int*)(buf + off);
    float a = h2f((unsigned short)(u & 0xFFFF));
    float b = h2f((unsigned short)(u >> 16));
    float c = fc[s_ * 32 + i];
    float sn = fs[s_ * 32 + i];
    float na = a * c - b * sn;
    float nb = a * sn + b * c;
    float sa = 1.f / (1.f + __expf(-na));
    float sb = 1.f / (1.f + __expf(-nb));
    unsigned int o = (unsigned int)f2h(sa) | ((unsigned int)f2h(sb) << 16);
    *(unsigned int*)(buf + off) = o;
}

// ---------------------------------------------------------------------------
// Per-(s,h) K row sums (f32) for the |.| relu trick.
// ---------------------------------------------------------------------------
__global__ __launch_bounds__(256) void ksum_kernel(const unsigned short* __restrict__ Kb,
                                                   float* __restrict__ Ksum) {
    int tid = threadIdx.x;
    int p = blockIdx.x * 64 + (tid >> 2);
    int dg = tid & 3;
    int s_ = p >> 4, h = p & 15;
    const unsigned short* kp = Kb + (size_t)s_ * DD + h * 64 + dg * 16;
    float t = 0.f;
#pragma unroll
    for (int j4 = 0; j4 < 4; ++j4) {
        ushort4 u = *(const ushort4*)(kp + j4 * 4);
        t += (h2f(u.x) + h2f(u.y)) + (h2f(u.z) + h2f(u.w));
    }
    t += __shfl_xor(t, 1);
    t += __shfl_xor(t, 2);
    if (dg == 0) Ksum[p] = t;
}

// ---------------------------------------------------------------------------
// Attention core.  t(q,k) = 0.5*(Sq - Sk + sum|q-k|); p = exp(-5t/64).
// Fixed softmax shift (score<=5) -> k-chunk partials additive.
// Block: 256 thr = 4 waves; wave w owns q rows qc*64+w*16 .. +16.
// Lane l: q row = l&15 (MFMA A-frag rows), k rows g*8+j (g=l>>4) -> p's land
// directly in the A operand of mfma_f32_16x16x32_f16; PV via 4 MFMAs/tile
// with Vt[d][s] B-frags loaded as contiguous half8 from global.
// K staged to LDS via global_load_lds (linear dest, XOR'd source -> swizzled
// content -> conflict-free broadcast ds_read_b128).
// Grid: 768 blocks = 16 heads x 48 work items (k-chunks of 1024), big first.
// ---------------------------------------------------------------------------
__global__ __launch_bounds__(256) void attn_kernel(const unsigned short* __restrict__ Qb,
                                                   const unsigned short* __restrict__ Kb,
                                                   const unsigned short* __restrict__ Vt,
                                                   const float* __restrict__ Ksum,
                                                   float* __restrict__ AO,
                                                   float* __restrict__ L) {
    __shared__ __align__(16) unsigned short Ks[2][32 * 64];
    __shared__ float Ksf[2][32];

    const int tid = threadIdx.x;
    const int l = tid & 63, w = tid >> 6;
    const int g = l >> 4, m = l & 15;

    // work item decode (big blocks first)
    const int bid = (int)blockIdx.x;
    const int h = bid & 15;
    const int r = 47 - (bid >> 4);
    int qc, kc;
    if (r < 16) { qc = r; kc = 0; }
    else { int rr = r - 16; qc = 16 + (rr >> 1); kc = rr & 1; }
    const int klo = kc << 10;
    int khi = (kc + 1) << 10;
    const int kcap = qc * 64 + 64;
    if (khi > kcap) khi = kcap;
    const int nt = (khi - klo) >> 5;
    const int qbase = qc * 64 + w * 16;
    const int qrow = qbase + m;

    const h2 one2 = {(_Float16)1.f, (_Float16)1.f};

    // load q row (64 dims) as 32 packed h2; compute Sq
    h2 qv[32];
    float sq = 0.f;
    {
        const uint4* qp = (const uint4*)(Qb + (size_t)qrow * DD + h * 64);
#pragma unroll
        for (int c = 0; c < 8; ++c) {
            uint4 qr4 = qp[c];
            h2 a0 = __builtin_bit_cast(h2, qr4.x);
            h2 a1 = __builtin_bit_cast(h2, qr4.y);
            h2 a2 = __builtin_bit_cast(h2, qr4.z);
            h2 a3 = __builtin_bit_cast(h2, qr4.w);
            qv[c * 4 + 0] = a0; qv[c * 4 + 1] = a1;
            qv[c * 4 + 2] = a2; qv[c * 4 + 3] = a3;
            sq = __builtin_amdgcn_fdot2(a0, one2, sq, false);
            sq = __builtin_amdgcn_fdot2(a1, one2, sq, false);
            sq = __builtin_amdgcn_fdot2(a2, one2, sq, false);
            sq = __builtin_amdgcn_fdot2(a3, one2, sq, false);
        }
    }

    // staging helper: tile t -> buf t&1.  Linear LDS dest (lane*16B), source
    // chunk XOR'd by wave id so reads (chunk i of row r at pos i^((r>>3)&3))
    // are bank-conflict-free.
    auto STAGE = [&](int t) {
        const int k0 = klo + (t << 5);
        const int buf = t & 1;
        const int row = (w << 3) + (l >> 3);
        const int seg = (l & 7) ^ w;
        const unsigned short* src = Kb + (size_t)(k0 + row) * DD + h * 64 + seg * 8;
        unsigned short* dst = &Ks[buf][w * 512];
        __builtin_amdgcn_global_load_lds(
            (const __attribute__((address_space(1))) void*)src,
            (__attribute__((address_space(3))) void*)dst, 16, 0, 0);
        if (tid < 32) Ksf[buf][tid] = Ksum[(size_t)(k0 + tid) * HH + h];
    };

    f32x4 acc[4] = {};
    float lsum = 0.f;
    const unsigned short* vbase = Vt + (size_t)(h * 64 + m) * SS;

    STAGE(0);
    __syncthreads();

    for (int t = 0; t < nt; ++t) {
        const int k0 = klo + (t << 5);
        if (t + 1 < nt) STAGE(t + 1);

        // V B-fragments (prefetch early; consumed at tile end)
        half8 vf[4];
#pragma unroll
        for (int dt = 0; dt < 4; ++dt)
            vf[dt] = *(const half8*)(vbase + (size_t)dt * 16 * SS + k0 + g * 8);

        const unsigned short* kp = &Ks[t & 1][g * 512];
        float tj[8];
#pragma unroll
        for (int j = 0; j < 8; ++j) tj[j] = 0.f;

#pragma unroll
        for (int ci = 0; ci < 8; ++ci) {
            const int co = ((ci ^ g) * 8);
#pragma unroll
            for (int j = 0; j < 8; ++j) {
                uint4 kr4 = *(const uint4*)(kp + j * 64 + co);
#pragma unroll
                for (int e = 0; e < 4; ++e) {
                    unsigned int ku = e == 0 ? kr4.x : (e == 1 ? kr4.y : (e == 2 ? kr4.z : kr4.w));
                    h2 d = qv[ci * 4 + e] - __builtin_bit_cast(h2, ku);
                    unsigned int du = __builtin_bit_cast(unsigned int, d) & 0x7FFF7FFFu;
                    tj[j] = __builtin_amdgcn_fdot2(__builtin_bit_cast(h2, du), one2, tj[j], false);
                }
            }
        }

        half8 a;
#pragma unroll
        for (int j = 0; j < 8; ++j) {
            float sk = Ksf[t & 1][g * 8 + j];
            float p = __expf(-0.0390625f * (sq - sk + tj[j]));
            p = (k0 + g * 8 + j <= qrow) ? p : 0.f;
            lsum += p;
            a[j] = (_Float16)p;
        }
#pragma unroll
        for (int dt = 0; dt < 4; ++dt)
            acc[dt] = __builtin_amdgcn_mfma_f32_16x16x32_f16(a, vf[dt], acc[dt], 0, 0, 0);

        __syncthreads();
    }

    // l: lane partial covers its 8-k subsets; reduce over the 4 groups
    lsum += __shfl_xor(lsum, 16);
    lsum += __shfl_xor(lsum, 32);
    if (l < 16) atomicAdd(&L[(size_t)(qbase + m) * HH + h], lsum);

    // C/D frag: row = 4g+e, col = m
    float* aop = AO + (size_t)(qbase + (g << 2)) * DD + h * 64 + m;
#pragma unroll
    for (int dt = 0; dt < 4; ++dt)
#pragma unroll
        for (int e = 0; e < 4; ++e)
            atomicAdd(aop + (size_t)e * DD + dt * 16, acc[dt][e]);
}

// ---------------------------------------------------------------------------
// Normalize AO by L and emit f16 for the output GEMM.
// ---------------------------------------------------------------------------
__global__ __launch_bounds__(256) void norm_kernel(const float* __restrict__ AO,
                                                   const float* __restrict__ L,
                                                   unsigned short* __restrict__ AOb) {
    int idx = blockIdx.x * 256 + threadIdx.x;
    int c4 = idx & 255;
    int s_ = idx >> 8;
    float inv = 1.f / L[s_ * HH + (c4 >> 4)];
    float4 v = ((const float4*)AO)[idx];
    ushort4 o;
    o.x = f2h(v.x * inv); o.y = f2h(v.y * inv);
    o.z = f2h(v.z * inv); o.w = f2h(v.w * inv);
    *(ushort4*)(AOb + (size_t)idx * 4) = o;
}

// ---------------------------------------------------------------------------
extern "C" void kernel_launch(void* const* d_in, const int* in_sizes, int n_in,
                              void* d_out, int out_size, void* d_ws, size_t ws_size,
                              hipStream_t stream) {
    const float* x  = (const float*)d_in[0];
    const float* fc = (const float*)d_in[1];
    const float* fs = (const float*)d_in[2];
    const float* Wq = (const float*)d_in[4];
    const float* Wk = (const float*)d_in[5];
    const float* Wv = (const float*)d_in[6];
    const float* Wo = (const float*)d_in[7];
    float* out = (float*)d_out;

    char* ws = (char*)d_ws;
    unsigned short* Xb  = (unsigned short*)(ws);                // 4 MB (reused AOb)
    unsigned short* Wt  = (unsigned short*)(ws + (4u << 20));   // 6 MB QKV^T f16
    unsigned short* Wot = (unsigned short*)(ws + (10u << 20));  // 2 MB Wo^T f16
    unsigned short* Qb  = (unsigned short*)(ws + (12u << 20));  // 4 MB
    unsigned short* Kb  = (unsigned short*)(ws + (16u << 20));  // 4 MB
    unsigned short* Vt  = (unsigned short*)(ws + (20u << 20));  // 4 MB  V transposed [d][s]
    float* AO   = (float*)(ws + (24u << 20));                   // 8 MB
    float* Lw   = (float*)(ws + (32u << 20));                   // 128 KB
    float* Ksum = (float*)(ws + (32u << 20) + SS * HH * 4);     // 128 KB
    unsigned short* AOb = Xb;

    cvt_f16<<<SD / 8 / 256, 256, 0, stream>>>(x, Xb);
    transpose_cvt<<<dim3(32, 32), dim3(32, 8), 0, stream>>>(Wq, Wt, DD, DD);
    transpose_cvt<<<dim3(32, 32), dim3(32, 8), 0, stream>>>(Wk, Wt + DD * DD, DD, DD);
    transpose_cvt<<<dim3(32, 32), dim3(32, 8), 0, stream>>>(Wv, Wt + 2 * DD * DD, DD, DD);
    transpose_cvt<<<dim3(32, 32), dim3(32, 8), 0, stream>>>(Wo, Wot, DD, DD);

    gemm_f16<0><<<dim3(24, 16), 256, 0, stream>>>(Xb, Wt, Qb, Kb, Vt, nullptr,
                                                  SS, 3 * DD, DD);
    rope_sig<<<8192, 256, 0, stream>>>(Qb, Kb, fc, fs);
    ksum_kernel<<<SS * HH / 64, 256, 0, stream>>>(Kb, Ksum);

    hipMemsetAsync(AO, 0, (size_t)SD * 4 + SS * HH * 4, stream);
    attn_kernel<<<768, 256, 0, stream>>>(Qb, Kb, Vt, Ksum, AO, Lw);
    norm_kernel<<<SD / 4 / 256, 256, 0, stream>>>(AO, Lw, AOb);

    gemm_f16<1><<<dim3(8, 16), 256, 0, stream>>>(AOb, Wot, nullptr, nullptr, nullptr,
                                                 out, SS, DD, DD);
}

// Round 12
// 221.710 us; speedup vs baseline: 6.1895x; 1.5313x over previous
//
#include <hip/hip_runtime.h>

#define SS 2048
#define DD 1024
#define HH 16
#define SD (SS*DD)

typedef __attribute__((ext_vector_type(8))) _Float16 half8;
typedef __attribute__((ext_vector_type(4))) float f32x4;

__device__ __forceinline__ float h2f(unsigned short u) {
    union { unsigned short s; _Float16 h; } v; v.s = u; return (float)v.h;
}
__device__ __forceinline__ unsigned short f2h(float f) {
    union { _Float16 h; unsigned short s; } v; v.h = (_Float16)f; return v.s;
}

// sad4(a,b,acc) = acc + sum of |a.byte_i - b.byte_i|
__device__ __forceinline__ unsigned int sad4(unsigned int a, unsigned int b, unsigned int acc) {
#if __has_builtin(__builtin_amdgcn_sad_u8)
    return __builtin_amdgcn_sad_u8(a, b, acc);
#else
    unsigned int s = acc;
#pragma unroll
    for (int i = 0; i < 4; ++i) {
        int av = (a >> (8 * i)) & 255, bv = (b >> (8 * i)) & 255;
        s += (av > bv) ? (av - bv) : (bv - av);
    }
    return s;
#endif
}

// ---------------------------------------------------------------------------
// fp32 -> f16 convert (x -> Xb), 8 elements/thread
// ---------------------------------------------------------------------------
__global__ __launch_bounds__(256) void cvt_f16(const float* __restrict__ X,
                                               unsigned short* __restrict__ Xb) {
    int i = (blockIdx.x * 256 + threadIdx.x) * 8;
    float4 f0 = *(const float4*)(X + i);
    float4 f1 = *(const float4*)(X + i + 4);
    ushort4 o0, o1;
    o0.x = f2h(f0.x); o0.y = f2h(f0.y); o0.z = f2h(f0.z); o0.w = f2h(f0.w);
    o1.x = f2h(f1.x); o1.y = f2h(f1.y); o1.z = f2h(f1.z); o1.w = f2h(f1.w);
    *(ushort4*)(Xb + i) = o0;
    *(ushort4*)(Xb + i + 4) = o1;
}

// ---------------------------------------------------------------------------
// All four weight transposes in one launch (z selects matrix).
// ---------------------------------------------------------------------------
__global__ __launch_bounds__(256) void transpose_all(const float* __restrict__ W0,
                                                     const float* __restrict__ W1,
                                                     const float* __restrict__ W2,
                                                     const float* __restrict__ W3,
                                                     unsigned short* __restrict__ Wqkv,
                                                     unsigned short* __restrict__ Wot) {
    __shared__ float T[32][33];
    const int z = blockIdx.z;
    const float* W = z == 0 ? W0 : (z == 1 ? W1 : (z == 2 ? W2 : W3));
    unsigned short* Wt = z < 3 ? (Wqkv + (size_t)z * DD * DD) : Wot;
    const int tx = threadIdx.x, ty = threadIdx.y;
    const int c0 = blockIdx.x * 32, r0 = blockIdx.y * 32;
#pragma unroll
    for (int j = 0; j < 4; ++j) {
        int r = ty * 4 + j;
        T[r][tx] = W[(size_t)(r0 + r) * DD + c0 + tx];
    }
    __syncthreads();
#pragma unroll
    for (int j = 0; j < 4; ++j) {
        int c = ty * 4 + j;
        Wt[(size_t)(c0 + c) * DD + r0 + tx] = f2h(T[tx][c]);
    }
}

// ---------------------------------------------------------------------------
// f16 MFMA GEMM: C[M,N] = A[M,K] @ Bt[N,K]^T.  128x128 tile, BK=32, 4 waves.
// MODE 0: cols [0,1024)->Qb f16, [1024,2048)->Kb f16,
//         [2048,3072)->Vt f16 TRANSPOSED (Vt[d][s], d = col-2048).
// MODE 1: write fp32 into Cf[M,N].
// ---------------------------------------------------------------------------
template <int MODE>
__global__ __launch_bounds__(256) void gemm_f16(const unsigned short* __restrict__ A,
                                                const unsigned short* __restrict__ Bt,
                                                unsigned short* __restrict__ Qo,
                                                unsigned short* __restrict__ Ko,
                                                unsigned short* __restrict__ Vt,
                                                float* __restrict__ Cf,
                                                int M, int N, int K) {
    __shared__ __align__(16) unsigned short As[128 * 32];
    __shared__ __align__(16) unsigned short Bs[128 * 32];
    const int tid = threadIdx.x;
    const int l = tid & 63, w = tid >> 6;
    const int wr = w >> 1, wc = w & 1;
    const int row0 = blockIdx.y * 128, col0 = blockIdx.x * 128;

    f32x4 acc[4][4] = {};

    for (int k0 = 0; k0 < K; k0 += 32) {
        __syncthreads();
#pragma unroll
        for (int it = 0; it < 2; ++it) {
            int f = it * 256 + tid;
            int r = f >> 2, seg = f & 3;
            *(half8*)&As[r * 32 + seg * 8] =
                *(const half8*)(A + (size_t)(row0 + r) * K + k0 + seg * 8);
            *(half8*)&Bs[r * 32 + seg * 8] =
                *(const half8*)(Bt + (size_t)(col0 + r) * K + k0 + seg * 8);
        }
        __syncthreads();
        half8 a[4], b[4];
#pragma unroll
        for (int m = 0; m < 4; ++m) {
            int r = wr * 64 + m * 16 + (l & 15);
            a[m] = *(const half8*)&As[r * 32 + (l >> 4) * 8];
        }
#pragma unroll
        for (int n = 0; n < 4; ++n) {
            int r = wc * 64 + n * 16 + (l & 15);
            b[n] = *(const half8*)&Bs[r * 32 + (l >> 4) * 8];
        }
#pragma unroll
        for (int m = 0; m < 4; ++m)
#pragma unroll
            for (int n = 0; n < 4; ++n)
                acc[m][n] = __builtin_amdgcn_mfma_f32_16x16x32_f16(a[m], b[n], acc[m][n], 0, 0, 0);
    }

    const int lr = (l >> 4) * 4, lc = l & 15;
    if (MODE == 0) {
        int third = col0 >> 10;
        if (third < 2) {
            unsigned short* Cp = third == 0 ? Qo : Ko;
            int cb = (col0 & 1023) + wc * 64;
#pragma unroll
            for (int m = 0; m < 4; ++m)
#pragma unroll
                for (int n = 0; n < 4; ++n)
#pragma unroll
                    for (int e = 0; e < 4; ++e) {
                        int row = row0 + wr * 64 + m * 16 + lr + e;
                        Cp[(size_t)row * DD + cb + n * 16 + lc] = f2h(acc[m][n][e]);
                    }
        } else {
            int cb = (col0 & 1023) + wc * 64;
#pragma unroll
            for (int m = 0; m < 4; ++m)
#pragma unroll
                for (int n = 0; n < 4; ++n) {
                    int dcol = cb + n * 16 + lc;
                    int srow = row0 + wr * 64 + m * 16 + lr;
                    ushort4 o;
                    o.x = f2h(acc[m][n][0]); o.y = f2h(acc[m][n][1]);
                    o.z = f2h(acc[m][n][2]); o.w = f2h(acc[m][n][3]);
                    *(ushort4*)(Vt + (size_t)dcol * SS + srow) = o;
                }
        }
    } else {
#pragma unroll
        for (int m = 0; m < 4; ++m)
#pragma unroll
            for (int n = 0; n < 4; ++n)
#pragma unroll
                for (int e = 0; e < 4; ++e) {
                    int row = row0 + wr * 64 + m * 16 + lr + e;
                    Cf[(size_t)row * N + col0 + wc * 64 + n * 16 + lc] = acc[m][n][e];
                }
    }
}

// ---------------------------------------------------------------------------
// RoPE + sigmoid -> u8 quantize (x255) for Q,K; fused per-(s,h) K u8 row sums
// (32 consecutive threads = one row; shfl reduce, lane 0 writes Ksq).
// ---------------------------------------------------------------------------
__global__ __launch_bounds__(256) void rope_sig(const unsigned short* __restrict__ Qb,
                                                const unsigned short* __restrict__ Kb,
                                                const float* __restrict__ fc,
                                                const float* __restrict__ fs,
                                                unsigned char* __restrict__ Q8,
                                                unsigned char* __restrict__ K8,
                                                float* __restrict__ Ksq) {
    int idx = blockIdx.x * 256 + threadIdx.x;
    int i = idx & 31;
    int h = (idx >> 5) & 15;
    int s_ = (idx >> 9) & 2047;
    int isK = idx >> 20;
    const unsigned short* buf = isK ? Kb : Qb;
    size_t off = (size_t)s_ * DD + h * 64 + 2 * i;
    unsigned int u = *(const unsigned int*)(buf + off);
    float a = h2f((unsigned short)(u & 0xFFFF));
    float b = h2f((unsigned short)(u >> 16));
    float c = fc[s_ * 32 + i];
    float sn = fs[s_ * 32 + i];
    float na = a * c - b * sn;
    float nb = a * sn + b * c;
    float sa = 1.f / (1.f + __expf(-na));
    float sb = 1.f / (1.f + __expf(-nb));
    unsigned int qa = (unsigned int)(sa * 255.f + 0.5f);
    unsigned int qb = (unsigned int)(sb * 255.f + 0.5f);
    unsigned char* o8 = isK ? K8 : Q8;
    *(unsigned short*)(o8 + off) = (unsigned short)(qa | (qb << 8));
    float ps = (float)(qa + qb);
    ps += __shfl_xor(ps, 1);
    ps += __shfl_xor(ps, 2);
    ps += __shfl_xor(ps, 4);
    ps += __shfl_xor(ps, 8);
    ps += __shfl_xor(ps, 16);
    if (isK && i == 0) Ksq[s_ * HH + h] = ps;
}

// ---------------------------------------------------------------------------
// Attention core (u8 SAD version).
// t_hat = 0.5*(Sq - Sk + SAD)/255 in quantized domain (exact relu identity);
// p = exp(CE*(Sq - Sk + SAD)), CE = -(5/64)*0.5/255.  Score<=5 fixed shift ->
// k-chunk partials additive.  Lane l: q row = l&15; k rows g*8+j (g=l>>4);
// p's land directly in MFMA A-frags; PV = mfma_f32_16x16x32_f16 vs Vt[d][s].
// K u8 staged 64 rows/tile via global_load_lds (4KB: 4 waves x 64 lanes x 16B),
// XOR'd source seg <-> XOR'd read pos (involution), conflict-free reads.
// Grid: 1280 = 16 heads x 80 items (k-chunks of 512), big-first.
// ---------------------------------------------------------------------------
__global__ __launch_bounds__(256) void attn_kernel(const unsigned char* __restrict__ Q8,
                                                   const unsigned char* __restrict__ K8,
                                                   const unsigned short* __restrict__ Vt,
                                                   const float* __restrict__ Ksq,
                                                   float* __restrict__ AO,
                                                   float* __restrict__ L) {
    __shared__ __align__(16) unsigned char Ks[2][64 * 64];
    __shared__ __align__(16) float Ksf[2][64];

    const int tid = threadIdx.x;
    const int l = tid & 63, w = tid >> 6;
    const int g = l >> 4, m = l & 15;
    const float CE = -1.5318627e-4f;   // -(5/64)*0.5/255

    const int bid = (int)blockIdx.x;
    const int h = bid & 15;
    const int r = 79 - (bid >> 4);
    int qc, kc;
    if (r < 8)       { qc = r;                  kc = 0; }
    else if (r < 24) { qc = 8 + ((r - 8) >> 1); kc = (r - 8) & 1; }
    else if (r < 48) { qc = 16 + (r - 24) / 3;  kc = (r - 24) % 3; }
    else             { qc = 24 + ((r - 48) >> 2); kc = (r - 48) & 3; }
    const int klo = kc << 9;
    int khi = klo + 512;
    const int kcap = qc * 64 + 64;
    if (khi > kcap) khi = kcap;
    const int ns = (khi - klo) >> 6;
    const int qbase = qc * 64 + w * 16;
    const int qrow = qbase + m;
    const int thr = w * 16 + m;
    const int g8 = g * 8;

    // Q row u8 (64 B) and its byte sum
    unsigned int q0, q1, q2, q3, q4, q5, q6, q7, q8, q9, q10, q11, q12, q13, q14, q15;
    {
        const uint4* qp = (const uint4*)(Q8 + (size_t)qrow * DD + h * 64);
        uint4 A = qp[0], B = qp[1], C = qp[2], Dv = qp[3];
        q0 = A.x;  q1 = A.y;  q2 = A.z;  q3 = A.w;
        q4 = B.x;  q5 = B.y;  q6 = B.z;  q7 = B.w;
        q8 = C.x;  q9 = C.y;  q10 = C.z; q11 = C.w;
        q12 = Dv.x; q13 = Dv.y; q14 = Dv.z; q15 = Dv.w;
    }
    unsigned int squ = 0;
    squ = sad4(q0, 0u, squ);  squ = sad4(q1, 0u, squ);  squ = sad4(q2, 0u, squ);  squ = sad4(q3, 0u, squ);
    squ = sad4(q4, 0u, squ);  squ = sad4(q5, 0u, squ);  squ = sad4(q6, 0u, squ);  squ = sad4(q7, 0u, squ);
    squ = sad4(q8, 0u, squ);  squ = sad4(q9, 0u, squ);  squ = sad4(q10, 0u, squ); squ = sad4(q11, 0u, squ);
    squ = sad4(q12, 0u, squ); squ = sad4(q13, 0u, squ); squ = sad4(q14, 0u, squ); squ = sad4(q15, 0u, squ);
    const float csq = CE * (float)squ;

    // conflict-free read offsets (content at pos c^g is source seg c)
    const int off0 = (0 ^ g) * 16, off1 = (1 ^ g) * 16, off2 = (2 ^ g) * 16, off3 = (3 ^ g) * 16;

    // stage 64-row u8 tile t -> buf t&1 (linear dest, XOR'd source segment)
    auto STAGE = [&](int t) {
        const int k0 = klo + (t << 6);
        const int b = t & 1;
        const int row = tid >> 2;
        const int seg = (tid & 3) ^ ((tid >> 5) & 3);
        const unsigned char* src = K8 + (size_t)(k0 + row) * DD + h * 64 + seg * 16;
        unsigned char* dst = &Ks[b][tid * 16];
        __builtin_amdgcn_global_load_lds(
            (const __attribute__((address_space(1))) void*)src,
            (__attribute__((address_space(3))) void*)dst, 16, 0, 0);
        if (tid < 64) Ksf[b][tid] = Ksq[(size_t)(k0 + tid) * HH + h];
    };

    f32x4 acc[4] = {};
    float lsum = 0.f;
    const unsigned short* vbase = Vt + (size_t)(h * 64 + m) * SS;

    STAGE(0);
    __syncthreads();

    for (int t = 0; t < ns; ++t) {
        const int k0 = klo + (t << 6);
        if (t + 1 < ns) STAGE(t + 1);
        const int b = t & 1;
        const bool diag = (k0 == qc * 64);          // wave-uniform
        const int thrq = diag ? thr : 127;          // 127 >= any (half*32+g*8+j)
        const unsigned char* gb = &Ks[b][g8 * 64];

#pragma unroll
        for (int half = 0; half < 2; ++half) {
            half8 vf0 = *(const half8*)(vbase + (size_t)0 * 16 * SS + k0 + half * 32 + g8);
            half8 vf1 = *(const half8*)(vbase + (size_t)1 * 16 * SS + k0 + half * 32 + g8);
            half8 vf2 = *(const half8*)(vbase + (size_t)2 * 16 * SS + k0 + half * 32 + g8);
            half8 vf3 = *(const half8*)(vbase + (size_t)3 * 16 * SS + k0 + half * 32 + g8);
            float4 skA = *(const float4*)&Ksf[b][half * 32 + g8];
            float4 skB = *(const float4*)&Ksf[b][half * 32 + g8 + 4];
            float skarr[8] = {skA.x, skA.y, skA.z, skA.w, skB.x, skB.y, skB.z, skB.w};

            half8 a;
#pragma unroll
            for (int j = 0; j < 8; ++j) {
                const unsigned char* rp = gb + (half * 32 + j) * 64;
                uint4 k0v = *(const uint4*)(rp + off0);
                uint4 k1v = *(const uint4*)(rp + off1);
                uint4 k2v = *(const uint4*)(rp + off2);
                uint4 k3v = *(const uint4*)(rp + off3);
                unsigned int s = 0;
                s = sad4(k0v.x, q0, s);  s = sad4(k0v.y, q1, s);  s = sad4(k0v.z, q2, s);  s = sad4(k0v.w, q3, s);
                s = sad4(k1v.x, q4, s);  s = sad4(k1v.y, q5, s);  s = sad4(k1v.z, q6, s);  s = sad4(k1v.w, q7, s);
                s = sad4(k2v.x, q8, s);  s = sad4(k2v.y, q9, s);  s = sad4(k2v.z, q10, s); s = sad4(k2v.w, q11, s);
                s = sad4(k3v.x, q12, s); s = sad4(k3v.y, q13, s); s = sad4(k3v.z, q14, s); s = sad4(k3v.w, q15, s);
                float eb = __builtin_fmaf(-CE, skarr[j], csq);
                float p = __expf(__builtin_fmaf(CE, (float)s, eb));
                p = (half * 32 + g8 + j <= thrq) ? p : 0.f;
                lsum += p;
                a[j] = (_Float16)p;
            }
            acc[0] = __builtin_amdgcn_mfma_f32_16x16x32_f16(a, vf0, acc[0], 0, 0, 0);
            acc[1] = __builtin_amdgcn_mfma_f32_16x16x32_f16(a, vf1, acc[1], 0, 0, 0);
            acc[2] = __builtin_amdgcn_mfma_f32_16x16x32_f16(a, vf2, acc[2], 0, 0, 0);
            acc[3] = __builtin_amdgcn_mfma_f32_16x16x32_f16(a, vf3, acc[3], 0, 0, 0);
        }
        __syncthreads();
    }

    lsum += __shfl_xor(lsum, 16);
    lsum += __shfl_xor(lsum, 32);
    if (l < 16) atomicAdd(&L[(size_t)(qbase + m) * HH + h], lsum);

    float* aop = AO + (size_t)(qbase + (g << 2)) * DD + h * 64 + m;
#pragma unroll
    for (int dt = 0; dt < 4; ++dt)
#pragma unroll
        for (int e = 0; e < 4; ++e)
            atomicAdd(aop + (size_t)e * DD + dt * 16, acc[dt][e]);
}

// ---------------------------------------------------------------------------
// Normalize AO by L and emit f16 for the output GEMM.
// ---------------------------------------------------------------------------
__global__ __launch_bounds__(256) void norm_kernel(const float* __restrict__ AO,
                                                   const float* __restrict__ L,
                                                   unsigned short* __restrict__ AOb) {
    int idx = blockIdx.x * 256 + threadIdx.x;
    int c4 = idx & 255;
    int s_ = idx >> 8;
    float inv = 1.f / L[s_ * HH + (c4 >> 4)];
    float4 v = ((const float4*)AO)[idx];
    ushort4 o;
    o.x = f2h(v.x * inv); o.y = f2h(v.y * inv);
    o.z = f2h(v.z * inv); o.w = f2h(v.w * inv);
    *(ushort4*)(AOb + (size_t)idx * 4) = o;
}

// ---------------------------------------------------------------------------
extern "C" void kernel_launch(void* const* d_in, const int* in_sizes, int n_in,
                              void* d_out, int out_size, void* d_ws, size_t ws_size,
                              hipStream_t stream) {
    const float* x  = (const float*)d_in[0];
    const float* fc = (const float*)d_in[1];
    const float* fs = (const float*)d_in[2];
    const float* Wq = (const float*)d_in[4];
    const float* Wk = (const float*)d_in[5];
    const float* Wv = (const float*)d_in[6];
    const float* Wo = (const float*)d_in[7];
    float* out = (float*)d_out;

    char* ws = (char*)d_ws;
    unsigned short* Xb  = (unsigned short*)(ws);                // 4 MB (reused AOb)
    unsigned short* Wt  = (unsigned short*)(ws + (4u << 20));   // 6 MB QKV^T f16
    unsigned short* Wot = (unsigned short*)(ws + (10u << 20));  // 2 MB Wo^T f16
    unsigned short* Qb  = (unsigned short*)(ws + (12u << 20));  // 4 MB f16 Q (rope in)
    unsigned short* Kb  = (unsigned short*)(ws + (16u << 20));  // 4 MB f16 K (rope in)
    unsigned short* Vt  = (unsigned short*)(ws + (20u << 20));  // 4 MB V^T [d][s]
    float* AO   = (float*)(ws + (24u << 20));                   // 8 MB
    float* Lw   = (float*)(ws + (32u << 20));                   // 128 KB
    float* Ksq  = (float*)(ws + (32u << 20) + SS * HH * 4);     // 128 KB
    // u8 Q/K overlay the (dead-after-gemm<0>) Wt region:
    unsigned char* Q8 = (unsigned char*)(ws + (4u << 20));      // 2 MB
    unsigned char* K8 = (unsigned char*)(ws + (6u << 20));      // 2 MB
    unsigned short* AOb = Xb;

    cvt_f16<<<SD / 8 / 256, 256, 0, stream>>>(x, Xb);
    transpose_all<<<dim3(32, 32, 4), dim3(32, 8), 0, stream>>>(Wq, Wk, Wv, Wo, Wt, Wot);

    gemm_f16<0><<<dim3(24, 16), 256, 0, stream>>>(Xb, Wt, Qb, Kb, Vt, nullptr,
                                                  SS, 3 * DD, DD);
    rope_sig<<<8192, 256, 0, stream>>>(Qb, Kb, fc, fs, Q8, K8, Ksq);

    hipMemsetAsync(AO, 0, (size_t)SD * 4 + SS * HH * 4, stream);
    attn_kernel<<<1280, 256, 0, stream>>>(Q8, K8, Vt, Ksq, AO, Lw);
    norm_kernel<<<SD / 4 / 256, 256, 0, stream>>>(AO, Lw, AOb);

    gemm_f16<1><<<dim3(8, 16), 256, 0, stream>>>(AOb, Wot, nullptr, nullptr, nullptr,
                                                 out, SS, DD, DD);
}